// Round 3
// baseline (263.444 us; speedup 1.0000x reference)
//
#include <hip/hip_runtime.h>
#include <hip/hip_fp16.h>

// ---------------------------------------------------------------------------
// InversePerspectiveProjection. R12 = R11 sample_k (kept: measured neutral vs
// R9, fewer insts) + NEW transpose_k attacking DRAM page efficiency.
//   k1 transpose: 256-px tiles. Wave reads 1 KB CONTIGUOUS per channel row
//                 (was 256 B chunks -> ~4x HBM page activations; transpose ran
//                 at ~60% of copy BW = "344 MB equivalent" for 206 MB moved).
//                 fp16-in-LDS 32 KB, 8B-slot XOR swizzle (staging b64 writes
//                 conflict-free, output b32 reads 2-way=free). Bijective XCD
//                 swizzle (2100 % 8 != 0).
//   k2 fused    : geometry -> {4 weights, row base}; ONE global_load_dwordx2
//                 per (pt,cam) covers the 2x2 block; xor32+xor16 reduce;
//                 LDS transpose -> coalesced NT stores. (unchanged from R11)
// Established floors: sample 512 B/(pt,cam) line traffic (R7 + R11 neutral on
// halved VMEM issue -> line-delivery-bound, not issue-bound); harness poison
// (~83 us x fills) + restores dominate dur_us.
// ---------------------------------------------------------------------------

#define N_IMG 6
#define C_CH  64
#define HI    224
#define WI    400
#define HW    (HI * WI)          // 89600
#define D_RES 8
#define H_RES 128
#define W_RES 128
#define P_TOT (D_RES * H_RES * W_RES)   // 131072
#define VOX   0.4f
#define ROWH2 (WI * 32)          // half2 units per image row (12800)

#define TPPB  256                // pixels per transpose tile
#define NTILE (HW / TPPB)        // 350 tiles per image
#define NTB   (N_IMG * NTILE)    // 2100 blocks

// ---------------- k1: transpose+convert (N,C,HW) fp32 -> (N,HW,C) fp16 -----
__global__ __launch_bounds__(256) void transpose_k(const float* __restrict__ in,
                                                   __half* __restrict__ outh) {
    // [c][256px] fp16, 64 x 8B slots per channel row, slot ^= (c>>2)&7
    __shared__ unsigned int tile32[64 * 128];    // 32 KB
    struct __align__(8) H4 { __half2 a, b; };

    // bijective XCD swizzle (m204 form): q=262, r=4
    const int q = NTB / 8, r = NTB % 8;
    int xcd = blockIdx.x & 7, idx = blockIdx.x >> 3;
    int bid = (xcd < r) ? xcd * (q + 1) + idx
                        : r * (q + 1) + (xcd - r) * q + idx;

    int n      = bid / NTILE;
    int s_base = (bid % NTILE) * TPPB;
    int t = threadIdx.x;
    int w = t >> 6, l = t & 63;

    // staging: wave w covers channels w*16..w*16+15; lane l reads float4 at
    // pixels 4l..4l+3 -> 64 lanes x 16 B = 1 KB contiguous per instruction.
    const float* inp = in + (size_t)n * C_CH * HW + s_base;
    H4* tl8 = (H4*)tile32;
#pragma unroll
    for (int i = 0; i < 16; ++i) {
        int c = w * 16 + i;
        const float4 v = *(const float4*)(inp + (size_t)c * HW + 4 * l);
        H4 pk;
        pk.a = __floats2half2_rn(v.x, v.y);      // pixels 4l, 4l+1 (low first)
        pk.b = __floats2half2_rn(v.z, v.w);      // pixels 4l+2, 4l+3
        tl8[c * 64 + (l ^ ((c >> 2) & 7))] = pk; // permuted-contiguous b64
    }
    __syncthreads();

    // output: thread t covers channel quad cq = t&15 (ch 4cq..4cq+3) of pixel
    // pair pp; 4 x b32 LDS reads (2-way banks), repack, 2 x 8 B stores.
    int cq = t & 15;
    int hc = cq & 7;                             // == (c>>2)&7 for c=4cq+j
    unsigned long long* o64 = (unsigned long long*)outh;
#pragma unroll
    for (int pass = 0; pass < 8; ++pass) {
        int pp = pass * 16 + (t >> 4);           // pixels 2pp, 2pp+1
        int gd = 2 * ((pp >> 1) ^ hc) + (pp & 1);
        unsigned int q0 = tile32[(4 * cq + 0) * 128 + gd];
        unsigned int q1 = tile32[(4 * cq + 1) * 128 + gd];
        unsigned int q2 = tile32[(4 * cq + 2) * 128 + gd];
        unsigned int q3 = tile32[(4 * cq + 3) * 128 + gd];
        // low halves -> pixel 2pp, high halves -> pixel 2pp+1
        unsigned long long e = (unsigned long long)(q0 & 0xffffu)
                             | ((unsigned long long)(q1 & 0xffffu) << 16)
                             | ((unsigned long long)(q2 & 0xffffu) << 32)
                             | ((unsigned long long)(q3 & 0xffffu) << 48);
        unsigned long long o = (unsigned long long)(q0 >> 16)
                             | ((unsigned long long)(q1 >> 16) << 16)
                             | ((unsigned long long)(q2 >> 16) << 32)
                             | ((unsigned long long)(q3 >> 16) << 48);
        size_t base = (size_t)(n * HW + s_base + 2 * pp) * 16 + cq;
        o64[base]      = e;
        o64[base + 16] = o;
    }
}

// ---------------- geometry for one (point, image) --------------------------
// Emits weights remapped onto the clamped 2x2 block at (by..by+1, bx..bx+1):
//   wout = inv6 * (wxA*wyA, wxB*wyA, wxA*wyB, wxB*wyB), zeros for invalid/mask
//   oout = half2-unit offset of (by, bx) pixel block.
__device__ __forceinline__ void make_rec(int p, int n,
                                         const float* __restrict__ Kmat,
                                         const float* __restrict__ Rmat,
                                         const float* __restrict__ Tvec,
                                         float4& wout, int& oout) {
#pragma clang fp contract(off)               // match numpy rounding (mask boundary)
    // flat p is meshgrid (H,W,D) order: p = ih*1024 + iw*8 + id
    int ih = p >> 10;
    int iw = (p >> 3) & (W_RES - 1);
    int id = p & (D_RES - 1);

    float px = ((float)ih - 63.5f) * VOX;
    float py = ((float)iw - 63.5f) * VOX;
    float pz = ((float)id - 3.5f) * VOX;

    const float* R = Rmat + n * 9;
    const float* K = Kmat + n * 9;
    const float* T = Tvec + n * 3;

    float cx = px * R[0] + py * R[1] + pz * R[2] + T[0];
    float cy = px * R[3] + py * R[4] + pz * R[5] + T[1];
    float cz = px * R[6] + py * R[7] + pz * R[8] + T[2];

    float pix0 = cx * K[0] + cy * K[1] + cz * K[2];
    float pix1 = cx * K[3] + cy * K[4] + cz * K[5];
    float pix2 = cx * K[6] + cy * K[7] + cz * K[8];

    if (pix2 < 0.1f) {
        wout = make_float4(0.0f, 0.0f, 0.0f, 0.0f);
        oout = n * (HW * 32);
        return;
    }
    float u = pix0 / pix2;
    float v = pix1 / pix2;
    float g0 = 2.0f * v / 223.0f - 1.0f;
    float g1 = 2.0f * u / 399.0f - 1.0f;
    float xs = ((g0 + 1.0f) * 400.0f - 1.0f) * 0.5f;
    float ys = ((g1 + 1.0f) * 224.0f - 1.0f) * 0.5f;
    xs = fminf(fmaxf(xs, -10.0f), 410.0f);
    ys = fminf(fmaxf(ys, -10.0f), 234.0f);
    float x0f = floorf(xs), y0f = floorf(ys);
    float wx = xs - x0f, wy = ys - y0f;
    int x0 = (int)x0f, y0 = (int)y0f;
    int x1 = x0 + 1, y1 = y0 + 1;

    int bx = min(max(x0, 0), WI - 2);
    int by = min(max(y0, 0), HI - 2);
    // weight of pixel q: (q==x0 ? 1-wx : q==x1 ? wx : 0) — folds validity+clamp
    float wxA = (bx     == x0) ? (1.0f - wx) : ((bx     == x1) ? wx : 0.0f);
    float wxB = (bx + 1 == x0) ? (1.0f - wx) : ((bx + 1 == x1) ? wx : 0.0f);
    float wyA = (by     == y0) ? (1.0f - wy) : ((by     == y1) ? wy : 0.0f);
    float wyB = (by + 1 == y0) ? (1.0f - wy) : ((by + 1 == y1) ? wy : 0.0f);

    const float inv6 = 1.0f / 6.0f;
    wout.x = wxA * wyA * inv6;                // row by  , pixel bx
    wout.y = wxB * wyA * inv6;                // row by  , pixel bx+1
    wout.z = wxA * wyB * inv6;                // row by+1, pixel bx
    wout.w = wxB * wyB * inv6;                // row by+1, pixel bx+1
    oout = n * (HW * 32) + (by * WI + bx) * 32;
}

// ---------------- k2: fused geometry + gather + transpose-write ------------
__global__ __launch_bounds__(256) void sample_k(const float* __restrict__ Kmat,
                                                const float* __restrict__ Rmat,
                                                const float* __restrict__ Tvec,
                                                const __half2* __restrict__ imgT2,
                                                float* __restrict__ out) {
    __shared__ float4 swt4[64 * N_IMG];       // 6 KB weights (component-read)
    __shared__ int    sof[64 * N_IMG];        // 1.5 KB row-base offsets
    __shared__ float  sout[64 * 66];          // 16.9 KB acc tile

    int t = threadIdx.x;
    // XCD-aware swizzle: each XCD gets a contiguous ih-slab (L2 locality)
    int bid    = ((blockIdx.x & 7) << 8) | (blockIdx.x >> 3);   // 2048 = 8*256
    int p_base = bid * 64;

    for (int i = t; i < 64 * N_IMG; i += 256) {
        float4 w; int o;
        make_rec(p_base + i / N_IMG, i % N_IMG, Kmat, Rmat, Tvec, w, o);
        swt4[i] = w;
        sof[i]  = o;
    }
    __syncthreads();

    // gather: one point per FULL wave, ONE dwordx2 per (pt,cam):
    //   lane = row*32 + px*16 + m  ->  8 B = 4 channels of (row by+row, pixel
    //   bx+px). Lanes 0..31 cover row by (256 B contiguous), lanes 32..63 row
    //   by+1 — per-lane addressing folds both rows into a single instruction.
    int lane = t & 63;
    int wv   = t >> 6;                        // wave 0..3 -> points wv*16..+15
    int k    = lane & 31;                     // within-row: px*16 + m
    int row  = lane >> 5;                     // 0: row by, 1: row by+1
    int sel  = row * 2 + (k >> 4);            // weight component (row,px)

    struct __align__(8) H2X2 { __half2 a, b; };
    const float*   swtF    = (const float*)swt4;
    const __half2* rowbase = imgT2 + row * ROWH2 + 2 * k;  // lane-constant part

#pragma unroll 4
    for (int j = 0; j < 16; ++j) {
        int pl = wv * 16 + j;                 // block-local point
        float4 acc = make_float4(0.0f, 0.0f, 0.0f, 0.0f);
#pragma unroll
        for (int n = 0; n < N_IMG; ++n) {
            int   rec = pl * N_IMG + n;
            float w   = swtF[rec * 4 + sel];  // broadcast ds_read_b32
            int   o   = sof[rec];             // broadcast ds_read_b32
            const H2X2 v = *(const H2X2*)(rowbase + o);   // global_load_dwordx2
            float2 lo = __half22float2(v.a);
            float2 hi = __half22float2(v.b);
            acc.x = fmaf(w, lo.x, acc.x);
            acc.y = fmaf(w, lo.y, acc.y);
            acc.z = fmaf(w, hi.x, acc.z);
            acc.w = fmaf(w, hi.y, acc.w);
        }
        // combine rows (xor32), then pixels (xor16)
        acc.x += __shfl_xor(acc.x, 32, 64);
        acc.y += __shfl_xor(acc.y, 32, 64);
        acc.z += __shfl_xor(acc.z, 32, 64);
        acc.w += __shfl_xor(acc.w, 32, 64);
        acc.x += __shfl_xor(acc.x, 16, 64);
        acc.y += __shfl_xor(acc.y, 16, 64);
        acc.z += __shfl_xor(acc.z, 16, 64);
        acc.w += __shfl_xor(acc.w, 16, 64);
        if (lane < 16) {                      // lane m holds ch 4m..4m+3
            *(float2*)&sout[pl * 66 + 4 * lane]     = make_float2(acc.x, acc.y);
            *(float2*)&sout[pl * 66 + 4 * lane + 2] = make_float2(acc.z, acc.w);
        }
    }
    __syncthreads();

    // output: out[c*P + p], lane = point -> 256 B coalesced NT stores
    // (out is never re-read: bypass L2 so the epilogue doesn't evict
    //  gather-resident imgT lines)
    int csub = t >> 6;
#pragma unroll
    for (int i = 0; i < 16; ++i) {
        int c = csub * 16 + i;
        __builtin_nontemporal_store(sout[lane * 66 + c],
                                    &out[(size_t)c * P_TOT + p_base + lane]);
    }
}

// ---------------------------------------------------------------------------
extern "C" void kernel_launch(void* const* d_in, const int* in_sizes, int n_in,
                              void* d_out, int out_size, void* d_ws, size_t ws_size,
                              hipStream_t stream) {
    const float* images = (const float*)d_in[0];
    const float* intr   = (const float*)d_in[1];
    const float* rot    = (const float*)d_in[2];
    const float* trans  = (const float*)d_in[3];

    __half* imgT = (__half*)d_ws;             // 6*89600*64*2 B = 68.8 MB
    float*  outp = (float*)d_out;

    transpose_k<<<NTB, 256, 0, stream>>>(images, imgT);
    sample_k<<<P_TOT / 64, 256, 0, stream>>>(intr, rot, trans,
                                             (const __half2*)imgT, outp);
}